// Round 8
// baseline (185.092 us; speedup 1.0000x reference)
//
#include <hip/hip_runtime.h>

#define KDIM 32768

// One block per output element (200 total).
// bid < 100  -> dgm1[i] = dot(I1[row(inds1,i)], p0)
// bid >= 100 -> dgm2[i] = dot(I2[row(inds2,i)], p1)
__global__ __launch_bounds__(512) void cubical_gather_matvec(
    const float* __restrict__ p0, const float* __restrict__ p1,
    const float* __restrict__ I1, const float* __restrict__ I2,
    const int* __restrict__ inds1, const int* __restrict__ inds2,
    float* __restrict__ out)
{
    const int bid = blockIdx.x;           // 0..199
    const float* p;
    const float* I;
    const int* inds;
    int i;
    if (bid < 100) { p = p0; I = I1; inds = inds1; i = bid; }
    else           { p = p1; I = I2; inds = inds2; i = bid - 100; }

    const int r = inds[2 * i];
    const int c = inds[2 * i + 1];
    const float* row = I + (size_t)(r * 28 + c) * KDIM;

    const int tid = threadIdx.x;
    const float4* row4 = (const float4*)row;
    const float4* p4   = (const float4*)p;

    float acc = 0.f;
    // KDIM/4 = 8192 float4; 512 threads -> 16 iters each, fully coalesced.
    #pragma unroll 4
    for (int j = tid; j < KDIM / 4; j += 512) {
        float4 a = row4[j];
        float4 b = p4[j];
        acc += a.x * b.x + a.y * b.y + a.z * b.z + a.w * b.w;
    }

    // wave-64 shuffle reduce
    #pragma unroll
    for (int off = 32; off > 0; off >>= 1)
        acc += __shfl_down(acc, off, 64);

    __shared__ float s[8];
    const int lane = tid & 63;
    const int wid  = tid >> 6;
    if (lane == 0) s[wid] = acc;
    __syncthreads();
    if (tid == 0) {
        float t = 0.f;
        #pragma unroll
        for (int w = 0; w < 8; ++w) t += s[w];
        out[bid] = t;
    }
}

extern "C" void kernel_launch(void* const* d_in, const int* in_sizes, int n_in,
                              void* d_out, int out_size, void* d_ws, size_t ws_size,
                              hipStream_t stream) {
    const float* p0    = (const float*)d_in[0];
    const float* p1    = (const float*)d_in[1];
    const float* I1    = (const float*)d_in[2];
    const float* I2    = (const float*)d_in[3];
    const int*   inds1 = (const int*)d_in[4];
    const int*   inds2 = (const int*)d_in[5];
    float* out = (float*)d_out;

    cubical_gather_matvec<<<200, 512, 0, stream>>>(p0, p1, I1, I2, inds1, inds2, out);
}